// Round 2
// baseline (427.893 us; speedup 1.0000x reference)
//
#include <hip/hip_runtime.h>
#include <cstdint>

// Problem constants (fixed by reference setup_inputs):
//   N = 200000, M = 64, D = 256, K = 3
#define D_DIM 256
#define M_DIM 64
#define K_TOP 3

typedef unsigned long long u64;
typedef int   v4i __attribute__((ext_vector_type(4)));
typedef float v4f __attribute__((ext_vector_type(4)));

// ---------------------------------------------------------------------------
// Shared per-row top-3 body (identical semantics to the verified k2).
// 16-lane team owns one row; lane p owns neighbors 4p..4p+3 (one int4).
// counts ~ U[3,63] -> guard the int4 LOAD by 4p < cnt (masked lanes issue no
// memory request). Tie-break matches jax.lax.top_k (equal value -> lower
// index): key = (score_bits<<32)|(63-j); valid scores exp(...) > 0 so zeroed
// score bits are a safe knockout.
// ---------------------------------------------------------------------------
__device__ __forceinline__ void topk_row(
    const int* __restrict__ neighbors, const int* __restrict__ counts,
    const float* __restrict__ s_self,  const float* __restrict__ s_all,
    float* __restrict__ out_vals,      float* __restrict__ out_idx,
    int row, int sub, int p)
{
    const int   cnt = counts[row];     // uniform in team -> broadcast line
    const float ss  = s_self[row];

    v4i nb = (v4i){0, 0, 0, 0};
    if (p * 4 < cnt) {                 // skip fully-masked int4s entirely
        nb = __builtin_nontemporal_load(
            (const v4i*)(neighbors + (size_t)row * M_DIM) + p);
    }

    const int nbs[4] = { nb.x, nb.y, nb.z, nb.w };
    u64 key[4];
    #pragma unroll
    for (int e = 0; e < 4; ++e) {
        const int j = p * 4 + e;
        float score = 0.0f;
        if (j < cnt) {
            const float x  = ss + s_all[nbs[e]];   // L2-resident gather
            const float lr = (x >= 0.0f) ? x : 0.01f * x;
            score = expf(lr);
        }
        key[e] = ((u64)__float_as_uint(score) << 32) | (u64)(63 - j);
    }

    float vals[K_TOP];
    int   idxs[K_TOP];

    #pragma unroll
    for (int k = 0; k < K_TOP; ++k) {
        u64 m = key[0];
        if (key[1] > m) m = key[1];
        if (key[2] > m) m = key[2];
        if (key[3] > m) m = key[3];
        #pragma unroll
        for (int off = 8; off > 0; off >>= 1) {
            const u64 o = __shfl_xor(m, off);
            if (o > m) m = o;
        }
        const int jwin = 63 - (int)(m & 0x3F);
        vals[k] = __uint_as_float((unsigned)(m >> 32));

        const int ew = jwin & 3;       // element within owner's int4
        const int pw = jwin >> 2;      // owner lane within team
        const int cand = (ew == 0) ? nbs[0] : (ew == 1) ? nbs[1]
                       : (ew == 2) ? nbs[2] : nbs[3];
        idxs[k] = __shfl(cand, (sub << 4) | pw);   // owner was active (jwin<cnt)

        if (p == pw) {                 // owner knocks out the winning element
            const u64 dead = (u64)(63 - jwin);
            if      (ew == 0) key[0] = dead;
            else if (ew == 1) key[1] = dead;
            else if (ew == 2) key[2] = dead;
            else              key[3] = dead;
        }
    }

    if (p == 0) {
        const size_t base = (size_t)row * K_TOP;
        #pragma unroll
        for (int k = 0; k < K_TOP; ++k) {
            out_vals[base + k] = vals[k];
            out_idx [base + k] = (float)idxs[k];
        }
    }
}

// ---------------------------------------------------------------------------
// Barrier-counter init. The workspace is re-poisoned every iteration, so the
// counter must be re-zeroed by an enqueued kernel (graph-capture legal).
// Kernel completion publishes the store device-wide (implicit release).
// ---------------------------------------------------------------------------
__global__ void ns_bar_init(unsigned* __restrict__ bar) { *bar = 0u; }

// ---------------------------------------------------------------------------
// Fused persistent kernel with a SOFTWARE grid barrier (no cooperative API:
// a captured cooperative launch is the prime suspect for last round's
// container hang). Grid is capped host-side at occupancy*CUs so every block
// is co-resident -> arrive-and-spin cannot deadlock. Spin uses s_sleep and
// device-scope atomics; __threadfence() release/acquire makes phase-1's
// plain s_all/s_self stores visible across the 8 non-coherent XCD L2s.
//
// Phase 1: dual GEMV (grid-stride, 4 rows/wave, 16 lanes/row). W fragments
//          preloaded ONCE per persistent thread. nf streamed nontemporally
//          (read-once; keep L2 for phase-2's s_all gathers + neighbors).
// Phase 2: identical verified top-3 body, same row mapping.
// ---------------------------------------------------------------------------
__global__ __launch_bounds__(256) void ns_fused_sw(
    const float* __restrict__ nf,        // (N, 256)
    const int*   __restrict__ neighbors, // (N, 64)
    const int*   __restrict__ counts,    // (N,)
    const float* __restrict__ W,         // (512,)
    const float* __restrict__ b,         // (1,)
    float* __restrict__ s_self,          // (N,)
    float* __restrict__ s_all,           // (N,)
    unsigned* __restrict__ bar,          // grid barrier counter (zeroed)
    float* __restrict__ out_vals,        // (N, 3)
    float* __restrict__ out_idx,         // (N, 3)
    int N)
{
    const int lane = threadIdx.x & 63;
    const int sub  = lane >> 4;          // row slot within wave
    const int p    = lane & 15;          // lane within 16-lane team
    const int wid  = (int)((blockIdx.x * blockDim.x + threadIdx.x) >> 6);
    const int nw   = (int)((gridDim.x * blockDim.x) >> 6);
    const int nGroups = (N + 3) >> 2;    // groups of 4 rows

    // Per-lane W fragments: lane p always consumes wa4/wb4[i*16+p].
    const v4f* __restrict__ wa4 = (const v4f*)W;
    const v4f* __restrict__ wb4 = (const v4f*)(W + D_DIM);
    v4f wa_r[4], wb_r[4];
    #pragma unroll
    for (int i = 0; i < 4; ++i) {
        wa_r[i] = wa4[i * 16 + p];
        wb_r[i] = wb4[i * 16 + p];
    }
    const float bias = b[0];

    // ---- Phase 1: s_self / s_all ----
    for (int g = wid; g < nGroups; g += nw) {
        const int row = g * 4 + sub;
        if (row < N) {
            const v4f* __restrict__ vrow = (const v4f*)(nf + (size_t)row * D_DIM);
            float sa = 0.0f, sb = 0.0f;
            #pragma unroll
            for (int i = 0; i < 4; ++i) {
                const v4f v = __builtin_nontemporal_load(vrow + (i * 16 + p));
                sa += v.x * wa_r[i].x + v.y * wa_r[i].y
                    + v.z * wa_r[i].z + v.w * wa_r[i].w;
                sb += v.x * wb_r[i].x + v.y * wb_r[i].y
                    + v.z * wb_r[i].z + v.w * wb_r[i].w;
            }
            // 16-lane tree reduce (xor offsets 8..1 stay inside the team).
            #pragma unroll
            for (int off = 8; off > 0; off >>= 1) {
                sa += __shfl_xor(sa, off);
                sb += __shfl_xor(sb, off);
            }
            if (p == 0) {
                s_self[row] = sa + bias;
                s_all[row]  = sb;
            }
        }
    }

    // ---- Software grid barrier (all blocks co-resident by construction) ----
    __syncthreads();                     // whole block done with phase 1
    if (threadIdx.x == 0) {
        __threadfence();                 // release: publish s_self/s_all
        __hip_atomic_fetch_add(bar, 1u, __ATOMIC_ACQ_REL,
                               __HIP_MEMORY_SCOPE_AGENT);
        const unsigned target = gridDim.x;
        while (__hip_atomic_load(bar, __ATOMIC_ACQUIRE,
                                 __HIP_MEMORY_SCOPE_AGENT) < target) {
            __builtin_amdgcn_s_sleep(8);
        }
        __threadfence();                 // acquire: see other blocks' stores
    }
    __syncthreads();

    // ---- Phase 2: top-3 per row ----
    for (int g = wid; g < nGroups; g += nw) {
        const int row = g * 4 + sub;
        if (row < N) {
            topk_row(neighbors, counts, s_self, s_all, out_vals, out_idx,
                     row, sub, p);
        }
    }
}

// ---------------------------------------------------------------------------
// Fallback path: the verified two-kernel baseline (337 us), used only if the
// occupancy query fails.
// ---------------------------------------------------------------------------
__global__ __launch_bounds__(256) void ns_scores_kernel(
    const float* __restrict__ nf, const float* __restrict__ W,
    const float* __restrict__ b,  float* __restrict__ s_self,
    float* __restrict__ s_all, int N)
{
    const int wave = (blockIdx.x * blockDim.x + threadIdx.x) >> 6;
    const int lane = threadIdx.x & 63;
    const int sub  = lane >> 4;
    const int p    = lane & 15;
    const int row  = wave * 4 + sub;
    if (row >= N) return;

    const v4f* __restrict__ vrow = (const v4f*)(nf + (size_t)row * D_DIM);
    const v4f* __restrict__ wa4  = (const v4f*)W;
    const v4f* __restrict__ wb4  = (const v4f*)(W + D_DIM);

    float sa = 0.0f, sb = 0.0f;
    #pragma unroll
    for (int i = 0; i < 4; ++i) {
        const int o = i * 16 + p;
        const v4f v = vrow[o];
        const v4f a = wa4[o];
        const v4f c = wb4[o];
        sa += v.x * a.x + v.y * a.y + v.z * a.z + v.w * a.w;
        sb += v.x * c.x + v.y * c.y + v.z * c.z + v.w * c.w;
    }
    #pragma unroll
    for (int off = 8; off > 0; off >>= 1) {
        sa += __shfl_xor(sa, off);
        sb += __shfl_xor(sb, off);
    }
    if (p == 0) {
        s_self[row] = sa + b[0];
        s_all[row]  = sb;
    }
}

__global__ __launch_bounds__(256) void ns_topk_kernel(
    const int* __restrict__ neighbors, const int* __restrict__ counts,
    const float* __restrict__ s_self,  const float* __restrict__ s_all,
    float* __restrict__ out_vals,      float* __restrict__ out_idx, int N)
{
    const int wave = (blockIdx.x * blockDim.x + threadIdx.x) >> 6;
    const int lane = threadIdx.x & 63;
    const int sub  = lane >> 4;
    const int p    = lane & 15;
    const int row  = wave * 4 + sub;
    if (row >= N) return;
    topk_row(neighbors, counts, s_self, s_all, out_vals, out_idx, row, sub, p);
}

extern "C" void kernel_launch(void* const* d_in, const int* in_sizes, int n_in,
                              void* d_out, int out_size, void* d_ws, size_t ws_size,
                              hipStream_t stream)
{
    const float* nf        = (const float*)d_in[0];   // (N, 256)
    const int*   neighbors = (const int*)  d_in[1];   // (N, 64)
    const int*   counts    = (const int*)  d_in[2];   // (N,)
    const float* W         = (const float*)d_in[3];   // (512,)
    const float* b         = (const float*)d_in[4];   // (1,)

    const int N = in_sizes[2];

    float*    s_self = (float*)d_ws;                  // N floats
    float*    s_all  = s_self + N;                    // N floats
    unsigned* bar    = (unsigned*)(s_all + N);        // 1 u32 (re-zeroed by k0)

    float* out_vals = (float*)d_out;                  // N*3
    float* out_idx  = out_vals + (size_t)N * K_TOP;   // N*3 (indices as float)

    const int threads = 256;                          // 4 waves -> 16 rows/block
    const int rowsPerBlock = (threads / 64) * 4;
    const int needBlocks = (N + rowsPerBlock - 1) / rowsPerBlock;

    // One-time host-side capacity query (pure host calls, graph-capture safe).
    // fusedBlocksMax: >0 = co-resident block capacity; -1 = use fallback.
    static int fusedBlocksMax = 0;
    if (fusedBlocksMax == 0) {
        int bpc = 0, dev = 0;
        hipDeviceProp_t prop;
        hipError_t e1 = hipOccupancyMaxActiveBlocksPerMultiprocessor(
            &bpc, ns_fused_sw, threads, 0);
        hipError_t e2 = hipGetDevice(&dev);
        hipError_t e3 = hipGetDeviceProperties(&prop, dev);
        if (e1 == hipSuccess && e2 == hipSuccess && e3 == hipSuccess &&
            bpc >= 1 && prop.multiProcessorCount >= 1) {
            fusedBlocksMax = bpc * prop.multiProcessorCount;
        } else {
            (void)hipGetLastError();
            fusedBlocksMax = -1;
        }
    }

    if (fusedBlocksMax > 0) {
        const int blocks = needBlocks < fusedBlocksMax ? needBlocks
                                                       : fusedBlocksMax;
        ns_bar_init<<<1, 1, 0, stream>>>(bar);
        ns_fused_sw<<<blocks, threads, 0, stream>>>(
            nf, neighbors, counts, W, b, s_self, s_all, bar,
            out_vals, out_idx, N);
    } else {
        ns_scores_kernel<<<needBlocks, threads, 0, stream>>>(nf, W, b,
                                                             s_self, s_all, N);
        ns_topk_kernel<<<needBlocks, threads, 0, stream>>>(neighbors, counts,
                                                           s_self, s_all,
                                                           out_vals, out_idx, N);
    }
}

// Round 3
// 337.165 us; speedup vs baseline: 1.2691x; 1.2691x over previous
//
#include <hip/hip_runtime.h>
#include <cstdint>

// Problem constants (fixed by reference setup_inputs):
//   N = 200000, M = 64, D = 256, K = 3
#define D_DIM 256
#define M_DIM 64
#define K_TOP 3

typedef unsigned long long u64;
typedef int   v4i __attribute__((ext_vector_type(4)));
typedef float v4f __attribute__((ext_vector_type(4)));

// ---------------------------------------------------------------------------
// Session facts (R0-R2 measured):
//  * dur_us = ~241 us of harness poison fills (2 x 819.2 MB @ ~6.8 TB/s,
//    visible as fillBufferAligned in top-5) + our kernels (~96 us combined;
//    each <120.4 us, never in top-5).
//  * ALL inputs (226 MB) are L3-resident across iterations: the fused-kernel
//    probe measured hbm_bytes = 7.3 MB/dispatch (0.2% of peak). HBM is NOT
//    our kernels' constraint; L3/L2 bandwidth and issue rate are.
//  * Grid-wide fusion is a measured LOSS (444 us): single-counter software
//    barrier serializes 2048 arrivals + spinner traffic on one cache line.
//    Cooperative launch hung the container under graph capture. Two plain
//    launches are the right structure.
//  * Prior session: persistent k1 + W-preload measured neutral-to-worse;
//    rank-by-s_all shortcut rejected (exp-collision ties would mismatch
//    jax.lax.top_k's lower-index tie-break in out_idx).
// ---------------------------------------------------------------------------

// Kernel 1: per-node dual dot product. 4 rows per wave, 16 lanes per row.
// Lane loads 4x float4 (64B of the 1KB row); W re-read per wave is an L1
// hit. Plain stores keep s_all resident in L2/L3 for k2's gathers.
__global__ __launch_bounds__(256) void ns_scores_kernel(
    const float* __restrict__ nf,      // (N, 256)
    const float* __restrict__ W,       // (512,)
    const float* __restrict__ b,       // (1,)
    float* __restrict__ s_self,        // (N,)
    float* __restrict__ s_all,         // (N,)
    int N)
{
    const int wave = (blockIdx.x * blockDim.x + threadIdx.x) >> 6;
    const int lane = threadIdx.x & 63;
    const int sub  = lane >> 4;        // row slot within wave
    const int p    = lane & 15;        // lane within 16-lane team
    const int row  = wave * 4 + sub;
    if (row >= N) return;

    const v4f* __restrict__ vrow = (const v4f*)(nf + (size_t)row * D_DIM);
    const v4f* __restrict__ wa4  = (const v4f*)W;
    const v4f* __restrict__ wb4  = (const v4f*)(W + D_DIM);

    float sa = 0.0f, sb = 0.0f;
    #pragma unroll
    for (int i = 0; i < 4; ++i) {
        const int o = i * 16 + p;
        const v4f v = vrow[o];
        const v4f a = wa4[o];
        const v4f c = wb4[o];
        sa += v.x * a.x + v.y * a.y + v.z * a.z + v.w * a.w;
        sb += v.x * c.x + v.y * c.y + v.z * c.z + v.w * c.w;
    }
    #pragma unroll
    for (int off = 8; off > 0; off >>= 1) {
        sa += __shfl_xor(sa, off);
        sb += __shfl_xor(sb, off);
    }
    if (p == 0) {
        s_self[row] = sa + b[0];
        s_all[row]  = sb;
    }
}

// Kernel 2: per-node score + top-3. 4 rows per wave; lane p owns neighbors
// 4p..4p+3 (one int4). counts ~ U[3,63] (mean 33) -> guard the int4 LOAD by
// 4p < cnt: masked lanes issue no memory request (~26 MB neighbor traffic).
// Neighbor stream nontemporal. Tie-break matches jax.lax.top_k (equal value
// -> lower index): key = (score_bits<<32)|(63-j); valid scores exp(...) > 0
// so zeroed score bits are a safe knockout.
//
// R3 change: branchless inner loop. nbs[e] is ALWAYS an in-bounds index
// (0 when the int4 load was skipped -> s_all[0] is an L1-hit broadcast), so
// gather + leaky + exp run unconditionally and a single select on j<cnt
// zeroes invalid scores. Removes 4 divergent exec-mask regions per wave;
// exp instruction count per wave is unchanged (any-lane-active executed it
// anyway), only the mask churn goes away.
__global__ __launch_bounds__(256) void ns_topk_kernel(
    const int* __restrict__ neighbors, // (N, 64) int32
    const int* __restrict__ counts,    // (N,)    int32
    const float* __restrict__ s_self,  // (N,)
    const float* __restrict__ s_all,   // (N,)
    float* __restrict__ out_vals,      // (N, 3)
    float* __restrict__ out_idx,       // (N, 3)  indices as float
    int N)
{
    const int wave = (blockIdx.x * blockDim.x + threadIdx.x) >> 6;
    const int lane = threadIdx.x & 63;
    const int sub  = lane >> 4;
    const int p    = lane & 15;
    const int row  = wave * 4 + sub;
    if (row >= N) return;

    const int   cnt = counts[row];     // uniform in team -> broadcast line
    const float ss  = s_self[row];

    v4i nb = (v4i){0, 0, 0, 0};
    if (p * 4 < cnt) {                 // skip fully-masked int4s entirely
        nb = __builtin_nontemporal_load(
            (const v4i*)(neighbors + (size_t)row * M_DIM) + p);
    }

    const int nbs[4] = { nb.x, nb.y, nb.z, nb.w };
    u64 key[4];
    #pragma unroll
    for (int e = 0; e < 4; ++e) {
        const int j = p * 4 + e;
        // Unconditional gather: index always in-bounds (0 for skipped int4s,
        // real neighbor for tail elements of a partially-valid int4).
        const float x  = ss + s_all[nbs[e]];       // L2-resident gather
        const float lr = (x >= 0.0f) ? x : 0.01f * x;
        const float sc = expf(lr);                 // finite for all inputs
        const float score = (j < cnt) ? sc : 0.0f; // select, not branch
        key[e] = ((u64)__float_as_uint(score) << 32) | (u64)(63 - j);
    }

    float vals[K_TOP];
    int   idxs[K_TOP];

    #pragma unroll
    for (int k = 0; k < K_TOP; ++k) {
        u64 m = key[0];
        if (key[1] > m) m = key[1];
        if (key[2] > m) m = key[2];
        if (key[3] > m) m = key[3];
        #pragma unroll
        for (int off = 8; off > 0; off >>= 1) {
            const u64 o = __shfl_xor(m, off);
            if (o > m) m = o;
        }
        const int jwin = 63 - (int)(m & 0x3F);
        vals[k] = __uint_as_float((unsigned)(m >> 32));

        const int ew = jwin & 3;       // element within owner's int4
        const int pw = jwin >> 2;      // owner lane within team
        const int cand = (ew == 0) ? nbs[0] : (ew == 1) ? nbs[1]
                       : (ew == 2) ? nbs[2] : nbs[3];
        idxs[k] = __shfl(cand, (sub << 4) | pw);   // owner was active (jwin<cnt)

        if (p == pw) {                 // owner knocks out the winning element
            const u64 dead = (u64)(63 - jwin);
            if      (ew == 0) key[0] = dead;
            else if (ew == 1) key[1] = dead;
            else if (ew == 2) key[2] = dead;
            else              key[3] = dead;
        }
    }

    if (p == 0) {
        const size_t base = (size_t)row * K_TOP;
        #pragma unroll
        for (int k = 0; k < K_TOP; ++k) {
            out_vals[base + k] = vals[k];
            out_idx [base + k] = (float)idxs[k];
        }
    }
}

extern "C" void kernel_launch(void* const* d_in, const int* in_sizes, int n_in,
                              void* d_out, int out_size, void* d_ws, size_t ws_size,
                              hipStream_t stream)
{
    const float* nf        = (const float*)d_in[0];   // (N, 256)
    const int*   neighbors = (const int*)  d_in[1];   // (N, 64)
    const int*   counts    = (const int*)  d_in[2];   // (N,)
    const float* W         = (const float*)d_in[3];   // (512,)
    const float* b         = (const float*)d_in[4];   // (1,)

    const int N = in_sizes[2];

    float* s_self = (float*)d_ws;                     // N floats
    float* s_all  = s_self + N;                       // N floats

    float* out_vals = (float*)d_out;                  // N*3
    float* out_idx  = out_vals + (size_t)N * K_TOP;   // N*3 (indices as float)

    const int threads = 256;                          // 4 waves -> 16 rows/block
    const int rowsPerBlock = (threads / 64) * 4;
    const int blocks = (N + rowsPerBlock - 1) / rowsPerBlock;

    ns_scores_kernel<<<blocks, threads, 0, stream>>>(nf, W, b, s_self, s_all, N);
    ns_topk_kernel<<<blocks, threads, 0, stream>>>(neighbors, counts, s_self, s_all,
                                                   out_vals, out_idx, N);
}

// Round 4
// 322.897 us; speedup vs baseline: 1.3252x; 1.0442x over previous
//
#include <hip/hip_runtime.h>
#include <cstdint>

// Problem constants (fixed by reference setup_inputs):
//   N = 200000, M = 64, D = 256, K = 3
#define D_DIM 256
#define M_DIM 64
#define K_TOP 3

typedef unsigned long long u64;
typedef int   v4i __attribute__((ext_vector_type(4)));
typedef float v4f __attribute__((ext_vector_type(4)));

// ---------------------------------------------------------------------------
// Session facts (R0-R3 measured):
//  * dur_us(337) = harness poison fills (1-2 x 819.2 MB @ ~6.8 TB/s, ~120.5 us
//    each, always the top-5 dispatches) + our two kernels (each <120.4 us,
//    never visible in top-5).
//  * ALL inputs (226 MB) are L3-resident across iterations: R2's fused probe
//    measured hbm_bytes = 7.3 MB/dispatch (0.2% of HBM peak). Our kernels are
//    bound by L3/L2 behavior, not HBM.
//  * Fusion with a sw grid barrier: measured LOSS (427.9 us; 444 us under
//    rocprof). Cooperative launch: hung the container. Two plain launches.
//  * Branchless k2 inner loop (R3): exactly neutral (337.16 vs 336.93).
//  * Prior session: persistent k1 + W-preload neutral-to-worse.
//  * Rejected on correctness: fast-exp / rank-by-s_all shortcuts. absmax sits
//    exactly at the 0.0625 threshold; any change to exp rounding risks
//    flipping a top-3 tie -> index-magnitude error in out_idx.
//
// R4 experiment (this file): k1 nf loads made NONTEMPORAL + batched.
// Mechanism: k1 streams 204.8 MB once-read data through the 32 MiB L2 with
// plain loads -> 205 MB of write-allocate churn per iteration. nt bypasses
// L1/L2 allocation (stream served from L3), eliminating the thrash. k2 is
// byte-identical to the verified R3 version for a clean A/B vs 337.16 us.
// ---------------------------------------------------------------------------

// Kernel 1: per-node dual dot product. 4 rows per wave, 16 lanes per row.
// Lane loads 4x float4 (64B of the 1KB row), nontemporal (read-once stream;
// do not allocate in L1/L2). W re-read per wave stays plain (L1 hit). Plain
// stores keep s_self/s_all resident in L2/L3 for k2.
__global__ __launch_bounds__(256) void ns_scores_kernel(
    const float* __restrict__ nf,      // (N, 256)
    const float* __restrict__ W,       // (512,)
    const float* __restrict__ b,       // (1,)
    float* __restrict__ s_self,        // (N,)
    float* __restrict__ s_all,         // (N,)
    int N)
{
    const int wave = (blockIdx.x * blockDim.x + threadIdx.x) >> 6;
    const int lane = threadIdx.x & 63;
    const int sub  = lane >> 4;        // row slot within wave
    const int p    = lane & 15;        // lane within 16-lane team
    const int row  = wave * 4 + sub;
    if (row >= N) return;

    const v4f* __restrict__ vrow = (const v4f*)(nf + (size_t)row * D_DIM);
    const v4f* __restrict__ wa4  = (const v4f*)W;
    const v4f* __restrict__ wb4  = (const v4f*)(W + D_DIM);

    // Batch the 4 streaming loads first (max memory-level parallelism),
    // then run the FMA chains.
    v4f v[4];
    #pragma unroll
    for (int i = 0; i < 4; ++i)
        v[i] = __builtin_nontemporal_load(vrow + (i * 16 + p));

    float sa = 0.0f, sb = 0.0f;
    #pragma unroll
    for (int i = 0; i < 4; ++i) {
        const v4f a = wa4[i * 16 + p];
        const v4f c = wb4[i * 16 + p];
        sa += v[i].x * a.x + v[i].y * a.y + v[i].z * a.z + v[i].w * a.w;
        sb += v[i].x * c.x + v[i].y * c.y + v[i].z * c.z + v[i].w * c.w;
    }
    #pragma unroll
    for (int off = 8; off > 0; off >>= 1) {
        sa += __shfl_xor(sa, off);
        sb += __shfl_xor(sb, off);
    }
    if (p == 0) {
        s_self[row] = sa + b[0];
        s_all[row]  = sb;
    }
}

// Kernel 2: per-node score + top-3 — BYTE-IDENTICAL to the verified R3
// version (clean A/B: only k1 changed this round).
__global__ __launch_bounds__(256) void ns_topk_kernel(
    const int* __restrict__ neighbors, // (N, 64) int32
    const int* __restrict__ counts,    // (N,)    int32
    const float* __restrict__ s_self,  // (N,)
    const float* __restrict__ s_all,   // (N,)
    float* __restrict__ out_vals,      // (N, 3)
    float* __restrict__ out_idx,       // (N, 3)  indices as float
    int N)
{
    const int wave = (blockIdx.x * blockDim.x + threadIdx.x) >> 6;
    const int lane = threadIdx.x & 63;
    const int sub  = lane >> 4;
    const int p    = lane & 15;
    const int row  = wave * 4 + sub;
    if (row >= N) return;

    const int   cnt = counts[row];     // uniform in team -> broadcast line
    const float ss  = s_self[row];

    v4i nb = (v4i){0, 0, 0, 0};
    if (p * 4 < cnt) {                 // skip fully-masked int4s entirely
        nb = __builtin_nontemporal_load(
            (const v4i*)(neighbors + (size_t)row * M_DIM) + p);
    }

    const int nbs[4] = { nb.x, nb.y, nb.z, nb.w };
    u64 key[4];
    #pragma unroll
    for (int e = 0; e < 4; ++e) {
        const int j = p * 4 + e;
        // Unconditional gather: index always in-bounds (0 for skipped int4s,
        // real neighbor for tail elements of a partially-valid int4).
        const float x  = ss + s_all[nbs[e]];       // L2-resident gather
        const float lr = (x >= 0.0f) ? x : 0.01f * x;
        const float sc = expf(lr);                 // finite for all inputs
        const float score = (j < cnt) ? sc : 0.0f; // select, not branch
        key[e] = ((u64)__float_as_uint(score) << 32) | (u64)(63 - j);
    }

    float vals[K_TOP];
    int   idxs[K_TOP];

    #pragma unroll
    for (int k = 0; k < K_TOP; ++k) {
        u64 m = key[0];
        if (key[1] > m) m = key[1];
        if (key[2] > m) m = key[2];
        if (key[3] > m) m = key[3];
        #pragma unroll
        for (int off = 8; off > 0; off >>= 1) {
            const u64 o = __shfl_xor(m, off);
            if (o > m) m = o;
        }
        const int jwin = 63 - (int)(m & 0x3F);
        vals[k] = __uint_as_float((unsigned)(m >> 32));

        const int ew = jwin & 3;       // element within owner's int4
        const int pw = jwin >> 2;      // owner lane within team
        const int cand = (ew == 0) ? nbs[0] : (ew == 1) ? nbs[1]
                       : (ew == 2) ? nbs[2] : nbs[3];
        idxs[k] = __shfl(cand, (sub << 4) | pw);   // owner was active (jwin<cnt)

        if (p == pw) {                 // owner knocks out the winning element
            const u64 dead = (u64)(63 - jwin);
            if      (ew == 0) key[0] = dead;
            else if (ew == 1) key[1] = dead;
            else if (ew == 2) key[2] = dead;
            else              key[3] = dead;
        }
    }

    if (p == 0) {
        const size_t base = (size_t)row * K_TOP;
        #pragma unroll
        for (int k = 0; k < K_TOP; ++k) {
            out_vals[base + k] = vals[k];
            out_idx [base + k] = (float)idxs[k];
        }
    }
}

extern "C" void kernel_launch(void* const* d_in, const int* in_sizes, int n_in,
                              void* d_out, int out_size, void* d_ws, size_t ws_size,
                              hipStream_t stream)
{
    const float* nf        = (const float*)d_in[0];   // (N, 256)
    const int*   neighbors = (const int*)  d_in[1];   // (N, 64)
    const int*   counts    = (const int*)  d_in[2];   // (N,)
    const float* W         = (const float*)d_in[3];   // (512,)
    const float* b         = (const float*)d_in[4];   // (1,)

    const int N = in_sizes[2];

    float* s_self = (float*)d_ws;                     // N floats
    float* s_all  = s_self + N;                       // N floats

    float* out_vals = (float*)d_out;                  // N*3
    float* out_idx  = out_vals + (size_t)N * K_TOP;   // N*3 (indices as float)

    const int threads = 256;                          // 4 waves -> 16 rows/block
    const int rowsPerBlock = (threads / 64) * 4;
    const int blocks = (N + rowsPerBlock - 1) / rowsPerBlock;

    ns_scores_kernel<<<blocks, threads, 0, stream>>>(nf, W, b, s_self, s_all, N);
    ns_topk_kernel<<<blocks, threads, 0, stream>>>(neighbors, counts, s_self, s_all,
                                                   out_vals, out_idx, N);
}